// Round 14
// baseline (368.023 us; speedup 1.0000x reference)
//
#include <hip/hip_runtime.h>
#include <math.h>

#define DEV __device__ __forceinline__
#define SB0() __builtin_amdgcn_sched_barrier(0)

typedef unsigned short u16;
typedef unsigned int   u32;
typedef __bf16 bf16x8 __attribute__((ext_vector_type(8)));
typedef float  f32x4  __attribute__((ext_vector_type(4)));
typedef u16    u16x8  __attribute__((ext_vector_type(8)));

// ---------- helpers ----------
DEV u16 f2b(float f) {                 // f32 -> bf16 RNE
  u32 u = __builtin_bit_cast(u32, f);
  u = (u + 0x7FFFu + ((u >> 16) & 1u)) >> 16;
  return (u16)u;
}
DEV float b2f(u16 h) { u32 u = (u32)h << 16; return __builtin_bit_cast(float, u); }

DEV void gl_lds16(const u16* g, u16* l) {  // async global->LDS, 16B/lane (lds ptr wave-uniform)
  __builtin_amdgcn_global_load_lds((const __attribute__((address_space(1))) void*)g,
                                   (__attribute__((address_space(3))) void*)l, 16, 0, 0);
}

// ============================================================================
// Fused prep: blockIdx ranges ->
//  [0,8192)       concat emb1|emb2 -> bf16 XB
//  [8192,8704)    Wq f32 -> bf16 row-major (Wqb)   [factored-scores operand]
//  [8704,9216)    Wk f32 -> bf16 row-major (Wkb)
//  [9216,9472)    Wv^T (1024x1024)
//  [9472,9984)    W1^T (1024x2048 -> 2048x1024)
//  [9984,10496)   W2^T (2048x1024 -> 1024x2048)
// (WqT/WkT transposes and bias-concat removed: Q,K are never materialized)
// ============================================================================
__global__ __launch_bounds__(256) void prep(
    const float* __restrict__ e1, const float* __restrict__ e2, u16* __restrict__ xb,
    const float* __restrict__ Wq, const float* __restrict__ Wk, const float* __restrict__ Wv,
    const float* __restrict__ W1, const float* __restrict__ W2,
    u16* __restrict__ Wqb, u16* __restrict__ Wkb,
    u16* __restrict__ WvT, u16* __restrict__ W1T, u16* __restrict__ W2T) {
  __shared__ float tile[64][65];
  const int bid = blockIdx.x;
  if (bid < 8192) {                       // concat+convert
    const size_t idx = ((size_t)bid * 256 + threadIdx.x) * 8;
    const int d = (int)(idx & 1023);
    const size_t row = idx >> 10;
    const float* s = (d < 512) ? (e1 + row * 512 + d) : (e2 + row * 512 + (d - 512));
    f32x4 a = *(const f32x4*)s;
    f32x4 b = *(const f32x4*)(s + 4);
    u16x8 o;
    o[0]=f2b(a[0]); o[1]=f2b(a[1]); o[2]=f2b(a[2]); o[3]=f2b(a[3]);
    o[4]=f2b(b[0]); o[5]=f2b(b[1]); o[6]=f2b(b[2]); o[7]=f2b(b[3]);
    *(u16x8*)(xb + idx) = o;
    return;
  }
  if (bid < 9216) {                       // plain f32->bf16 converts (Wq, Wk)
    const int base = (bid < 8704) ? 8192 : 8704;
    const float* src = (bid < 8704) ? Wq : Wk;
    u16* dst = (bid < 8704) ? Wqb : Wkb;
    const int off = ((bid - base) * 256 + threadIdx.x) * 8;
    f32x4 a = *(const f32x4*)(src + off);
    f32x4 b = *(const f32x4*)(src + off + 4);
    u16x8 o;
    o[0]=f2b(a[0]); o[1]=f2b(a[1]); o[2]=f2b(a[2]); o[3]=f2b(a[3]);
    o[4]=f2b(b[0]); o[5]=f2b(b[1]); o[6]=f2b(b[2]); o[7]=f2b(b[3]);
    *(u16x8*)(dst + off) = o;
    return;
  }
  const float* W; u16* WT; int ldi, ldo, bx, by;
  if (bid < 9472)      { W = Wv; WT = WvT; ldi = 1024; ldo = 1024; int v = bid - 9216; bx = v & 15; by = v >> 4; }
  else if (bid < 9984) { W = W1; WT = W1T; ldi = 2048; ldo = 1024; int v = bid - 9472; bx = v & 31; by = v >> 5; }
  else                 { W = W2; WT = W2T; ldi = 1024; ldo = 2048; int v = bid - 9984; bx = v & 15; by = v >> 4; }
  const int tx = threadIdx.x & 63, ty = threadIdx.x >> 6;
  const int r0 = by * 64, c0 = bx * 64;
#pragma unroll
  for (int i = 0; i < 16; ++i)
    tile[ty + 4*i][tx] = W[(size_t)(r0 + ty + 4*i) * ldi + c0 + tx];
  __syncthreads();
#pragma unroll
  for (int i = 0; i < 16; ++i)
    WT[(size_t)(c0 + ty + 4*i) * ldo + r0 + tx] = f2b(tile[tx][ty + 4*i]);
}

// ---------- bias vectors: vq = Wq.bk, vk = Wk.bq, cc = bq.bk ----------
__global__ __launch_bounds__(256) void bias_vecs(
    const float* __restrict__ Wq, const float* __restrict__ Wk,
    const float* __restrict__ bq, const float* __restrict__ bk,
    float* __restrict__ vq, float* __restrict__ vk, float* __restrict__ cc) {
  const int bid = blockIdx.x;
  if (bid == 512) {
    __shared__ float red[256];
    float s = 0.f;
    for (int i = threadIdx.x; i < 1024; i += 256) s += bq[i] * bk[i];
    red[threadIdx.x] = s; __syncthreads();
    for (int o = 128; o > 0; o >>= 1) {
      if ((int)threadIdx.x < o) red[threadIdx.x] += red[threadIdx.x + o];
      __syncthreads();
    }
    if (threadIdx.x == 0) cc[0] = red[0];
    return;
  }
  const float* W = (bid < 256) ? Wq : Wk;
  const float* b = (bid < 256) ? bk : bq;
  float* v = (bid < 256) ? vq : vk;
  const int row = ((bid & 255) << 2) + (threadIdx.x >> 6);
  const int ln = threadIdx.x & 63;
  const float* p = W + (size_t)row * 1024 + ln * 16;
  float s = 0.f;
#pragma unroll
  for (int m = 0; m < 16; ++m) s += p[m] * b[ln * 16 + m];
#pragma unroll
  for (int o = 32; o > 0; o >>= 1) s += __shfl_xor(s, o, 64);
  if (ln == 0) v[row] = s;
}

// ---------- u = X.vq + cc, w = X.vk (one pass over XB) ----------
__global__ __launch_bounds__(256) void uw_vecs(
    const u16* __restrict__ xb, const float* __restrict__ vq,
    const float* __restrict__ vk, const float* __restrict__ cc,
    float* __restrict__ U, float* __restrict__ W_) {
  const int row = blockIdx.x * 4 + (threadIdx.x >> 6);
  const int ln = threadIdx.x & 63;
  const u16* p = xb + (size_t)row * 1024 + ln * 16;
  u16x8 x0 = *(const u16x8*)p;
  u16x8 x1 = *(const u16x8*)(p + 8);
  float dq = 0.f, dk = 0.f;
#pragma unroll
  for (int m = 0; m < 8; ++m) {
    float xv = b2f(x0[m]);
    dq += xv * vq[ln * 16 + m]; dk += xv * vk[ln * 16 + m];
  }
#pragma unroll
  for (int m = 0; m < 8; ++m) {
    float xv = b2f(x1[m]);
    dq += xv * vq[ln * 16 + 8 + m]; dk += xv * vk[ln * 16 + 8 + m];
  }
#pragma unroll
  for (int o = 32; o > 0; o >>= 1) { dq += __shfl_xor(dq, o, 64); dk += __shfl_xor(dk, o, 64); }
  if (ln == 0) { U[row] = dq + cc[0]; W_[row] = dk; }
}

// ============================================================================
// 8-phase 256x256 template (r11 K-loop, best verified: 348.6us total).
// MODE epilogues:
//  0: bf16 out, col bias (nullable)      (MT, XM GEMMs use bias=nullptr)
//  1: bf16 out, col bias + relu          (MLP1)
//  2: bf16 out, ROW bias                 (V^T GEMM)
//  3: E = exp((acc + u[row] + w[col])*scale) masked, bf16 + atomic rowsum
//     (factored scores: acc = XM.X^T; u,w carry the bias rank-1 terms + c)
//  4: bf16 out, multiply by 1/rowsum[row]  (PV)
//  5: no C write: bias+relu, dot W3, atomicAdd logits (MLP2)
// Coalesced bf16 LDS-bounce store (r9-verified WRITE_SIZE == logical).
// ============================================================================
template<int MODE>
__global__ __launch_bounds__(512, 2) void gemm256(
    const u16* __restrict__ A, int lda, long long sA,
    const u16* __restrict__ B, int ldb, long long sB,
    void* __restrict__ C, int ldc, long long sC,
    const float* __restrict__ bias, float scale, int K,
    const int* __restrict__ mk1, const int* __restrict__ mk2,
    float* __restrict__ rsw, const float* __restrict__ uvec,
    const float* __restrict__ wvec, const float* __restrict__ w3,
    float* __restrict__ lg) {
  __shared__ __align__(16) u16 lds[2][2][16384];  // [buf][A/B][2half x 128r x 64c]

  const int t  = threadIdx.x;
  const int ln = t & 63, wv = t >> 6;

  // --- 2D-chunked bijective XCD swizzle (all grids have nwg % 8 == 0) ---
  int bx, by, bz;
  {
    const int gx = gridDim.x, gy = gridDim.y, gz = gridDim.z;
    const int nwg = gx * gy * gz;
    const int F = (blockIdx.z * gy + blockIdx.y) * gx + blockIdx.x;
    const int q = nwg >> 3;
    const int L = (F & 7) * q + (F >> 3);        // XCD k executes L in [k*q,(k+1)*q)
    if (gz > 1) {
      const int pb = gx * gy;
      bz = L / pb; const int r = L - bz * pb;
      by = r / gx; bx = r - by * gx;             // batch-major: whole batches per XCD
    } else {
      bz = 0;
      const int sh = ((gy & 7) == 0) ? 8 : 4;    // slab height
      const int sw = gx * sh;
      const int sy = L / sw; const int r = L - sy * sw;
      bx = r / sh; by = sy * sh + (r - bx * sh); // slab-major: A-slab resident per XCD
    }
  }
  const int m0 = by * 256, n0 = bx * 256;
  A += (size_t)bz * (size_t)sA; B += (size_t)bz * (size_t)sB;

  // staging bases: thread t covers (row t>>3, phys granule t&7) of a half-tile;
  // pre-swizzled logical granule gl = (ln&7) ^ (ln>>3)
  const int gl = (ln & 7) ^ (ln >> 3);
  const u16* gAs = A + (size_t)(m0 + (t >> 3)) * lda + gl * 8;
  const u16* gBs = B + (size_t)(n0 + (t >> 3)) * ldb + gl * 8;

  // read constants
  const int l15 = ln & 15, lhi = ln >> 4;
  const int wm = (wv >> 2) * 128, wn = (wv & 3) * 64;
  const int colk0 = ((lhi ^ (l15 & 7)) << 3);          // kslot 0 swizzled col (elems)
  const int colk1 = (((4 + lhi) ^ (l15 & 7)) << 3);    // kslot 1
  const int rcA = (wv >> 2) * 8192 + l15 * 64;         // A half + row base
  const int rcB = ((wv & 3) >> 1) * 8192 + (wv & 1) * 4096 + l15 * 64;

  f32x4 acc[8][4] = {};
  bf16x8 Af[4][2], Bf[4][2];
  const int KT = K >> 6, NIT = KT >> 1;

#define STG(T, OP, H, LD, GS)                                              \
  if ((T) < KT) {                                                          \
    const u16* _s = (GS) + (size_t)(H) * 128 * (size_t)(LD) + (size_t)(T) * 64; \
    u16* _d = &lds[(T) & 1][OP][(H) * 8192 + wv * 512];                    \
    gl_lds16(_s, _d); gl_lds16(_s + 64 * (size_t)(LD), _d + 4096);         \
  }
#define RDA(BUF, ILO) {                                                    \
  _Pragma("unroll") for (int ii = 0; ii < 4; ++ii) {                       \
    Af[ii][0] = *(const bf16x8*)&lds[BUF][0][rcA + ((ILO) + ii) * 1024 + colk0]; \
    Af[ii][1] = *(const bf16x8*)&lds[BUF][0][rcA + ((ILO) + ii) * 1024 + colk1]; } }
#define RDB(BUF, JLO) {                                                    \
  _Pragma("unroll") for (int jj = 0; jj < 2; ++jj) {                       \
    Bf[(JLO) + jj][0] = *(const bf16x8*)&lds[BUF][1][rcB + ((JLO) + jj) * 1024 + colk0]; \
    Bf[(JLO) + jj][1] = *(const bf16x8*)&lds[BUF][1][rcB + ((JLO) + jj) * 1024 + colk1]; } }
#define MM(ILO, JLO) {                                                     \
  _Pragma("unroll") for (int ii = 0; ii < 4; ++ii)                         \
  _Pragma("unroll") for (int jj = 0; jj < 2; ++jj) {                       \
    acc[(ILO)+ii][(JLO)+jj] = __builtin_amdgcn_mfma_f32_16x16x32_bf16(Af[ii][0], Bf[(JLO)+jj][0], acc[(ILO)+ii][(JLO)+jj], 0, 0, 0); \
    acc[(ILO)+ii][(JLO)+jj] = __builtin_amdgcn_mfma_f32_16x16x32_bf16(Af[ii][1], Bf[(JLO)+jj][1], acc[(ILO)+ii][(JLO)+jj], 0, 0, 0); } }
#define BAR() __builtin_amdgcn_s_barrier()
#define PRIO(x) __builtin_amdgcn_s_setprio(x)

  // prologue: T0 all 4 halves + T1's B halves; vmcnt(4) -> T0 landed
  STG(0, 0, 0, lda, gAs); STG(0, 0, 1, lda, gAs);
  STG(0, 1, 0, ldb, gBs); STG(0, 1, 1, ldb, gBs);
  STG(1, 1, 0, ldb, gBs); STG(1, 1, 1, ldb, gBs);
  asm volatile("s_waitcnt vmcnt(4)" ::: "memory");
  SB0(); BAR();

  for (int it = 0; it < NIT; ++it) {
    const int T0 = it << 1, T1 = T0 + 1;
    // ---- P1: Q0 of T0 ----
    RDB(0, 0); RDA(0, 0); STG(T1, 0, 0, lda, gAs);
    BAR();
    PRIO(1); MM(0, 0); PRIO(0); BAR();
    // ---- P2: Q1 of T0 ----
    RDB(0, 2); STG(T1, 0, 1, lda, gAs);
    BAR();
    PRIO(1); MM(0, 2); PRIO(0); BAR();
    // ---- P3: Q2 of T0 ----
    RDA(0, 4); STG(T0 + 2, 1, 0, ldb, gBs);
    BAR();
    PRIO(1); MM(4, 0); PRIO(0); BAR();
    // ---- P4: Q3 of T0 + counted vmcnt ----
    STG(T0 + 2, 1, 1, ldb, gBs);
    BAR();
    PRIO(1); MM(4, 2); PRIO(0);
    if (T0 + 2 < KT) { asm volatile("s_waitcnt vmcnt(4)" ::: "memory"); }
    else             { asm volatile("s_waitcnt vmcnt(0)" ::: "memory"); }
    SB0(); BAR();
    // ---- P5: Q0 of T1 ----
    RDB(1, 0); RDA(1, 0); STG(T0 + 2, 0, 0, lda, gAs);
    BAR();
    PRIO(1); MM(0, 0); PRIO(0); BAR();
    // ---- P6: Q1 of T1 ----
    RDB(1, 2); STG(T0 + 2, 0, 1, lda, gAs);
    BAR();
    PRIO(1); MM(0, 2); PRIO(0); BAR();
    // ---- P7: Q2 of T1 ----
    RDA(1, 4); STG(T0 + 3, 1, 0, ldb, gBs);
    BAR();
    PRIO(1); MM(4, 0); PRIO(0); BAR();
    // ---- P8: Q3 of T1 + counted vmcnt ----
    STG(T0 + 3, 1, 1, ldb, gBs);
    BAR();
    PRIO(1); MM(4, 2); PRIO(0);
    if (T0 + 3 < KT) { asm volatile("s_waitcnt vmcnt(4)" ::: "memory"); }
    SB0(); BAR();
  }
#undef STG
#undef RDA
#undef RDB
#undef MM
#undef BAR
#undef PRIO

  // ---------------- epilogue (frag D row=(lhi*4+r), col=l15; m89-verified) ----------------
  const size_t cb = (size_t)bz * (size_t)sC;

  if (MODE == 5) {
    // MLP2: bias+relu, dot W3 -> atomic logits; no C write.
    float w3v[4];
#pragma unroll
    for (int j = 0; j < 4; ++j) w3v[j] = w3[n0 + wn + j * 16 + l15];
#pragma unroll
    for (int i = 0; i < 8; ++i) {
      const int rg = m0 + wm + i * 16 + lhi * 4;
#pragma unroll
      for (int r = 0; r < 4; ++r) {
        float s = 0.f;
#pragma unroll
        for (int j = 0; j < 4; ++j) {
          float v = acc[i][j][r] + bias[n0 + wn + j * 16 + l15];
          v = fmaxf(v, 0.f);
          s += v * w3v[j];
        }
        s += __shfl_xor(s, 1, 64); s += __shfl_xor(s, 2, 64);
        s += __shfl_xor(s, 4, 64); s += __shfl_xor(s, 8, 64);
        if (l15 == 0) atomicAdd(&lg[rg + r], s);
      }
    }
    return;
  }

  u16* ep = ((u16*)lds) + wv * 8192;  // [128 rows][64 cols] wave-private bounce

  if (MODE == 3) {
    // factored scores: E = exp((acc + u[row] + w[col]) * scale) masked,
    // bf16 out + rowsum of quantized E.
    float wv4[4];
#pragma unroll
    for (int j = 0; j < 4; ++j)
      wv4[j] = wvec[(size_t)bz * 1024 + n0 + wn + j * 16 + l15];
#pragma unroll
    for (int i = 0; i < 8; ++i) {
#pragma unroll
      for (int r = 0; r < 4; ++r) {
        const int rr = m0 + wm + i * 16 + lhi * 4 + r;      // row in [0,1024)
        const int mk = (rr < 512) ? mk1[bz * 512 + rr] : mk2[bz * 512 + rr - 512];
        const float uq = uvec[(size_t)bz * 1024 + rr];
        const int lrow = i * 16 + lhi * 4 + r;
        float s = 0.f;
#pragma unroll
        for (int j = 0; j < 4; ++j) {
          float e = (mk != 0) ? __expf((acc[i][j][r] + uq + wv4[j]) * scale) : 0.f;
          const u16 eb = f2b(e);
          s += b2f(eb);
          const int lcol = (j * 16 + l15) ^ (((lrow >> 2) & 7) << 3);
          ep[lrow * 64 + lcol] = eb;
        }
        s += __shfl_xor(s, 1, 64); s += __shfl_xor(s, 2, 64);
        s += __shfl_xor(s, 4, 64); s += __shfl_xor(s, 8, 64);
        if (l15 == 0) atomicAdd(&rsw[(size_t)bz * 1024 + rr], s);
      }
    }
  } else {
    // MODE 0/1/2/4
#pragma unroll
    for (int i = 0; i < 8; ++i) {
      const int rl = wm + i * 16 + lhi * 4;
      float rv[4];
#pragma unroll
      for (int r = 0; r < 4; ++r) {
        if (MODE == 2)      rv[r] = bias[m0 + rl + r];
        else if (MODE == 4) rv[r] = 1.f / rsw[(size_t)bz * 1024 + m0 + rl + r];
        else                rv[r] = 0.f;
      }
#pragma unroll
      for (int j = 0; j < 4; ++j) {
        const float cbv = ((MODE == 0 || MODE == 1) && bias) ? bias[n0 + wn + j * 16 + l15] : 0.f;
#pragma unroll
        for (int r = 0; r < 4; ++r) {
          float v;
          if (MODE == 4)      v = acc[i][j][r] * rv[r];
          else if (MODE == 2) v = acc[i][j][r] + rv[r];
          else                v = acc[i][j][r] + cbv;
          if (MODE == 1) v = fmaxf(v, 0.f);
          const int lrow = i * 16 + lhi * 4 + r;
          const int lcol = (j * 16 + l15) ^ (((lrow >> 2) & 7) << 3);
          ep[lrow * 64 + lcol] = f2b(v);
        }
      }
    }
  }
  asm volatile("s_waitcnt lgkmcnt(0)" ::: "memory");  // own bounce writes landed
  SB0();
  const int l3 = ln >> 3, c0 = (ln & 7) * 8;
#pragma unroll
  for (int rep = 0; rep < 16; ++rep) {
    const int lr = rep * 8 + l3;
    const int cs = c0 ^ (((lr >> 2) & 7) << 3);
    u16x8 v = *(const u16x8*)&ep[lr * 64 + cs];
    *(u16x8*)((u16*)C + cb + (size_t)(m0 + wm + lr) * ldc + n0 + wn + c0) = v;
  }
}

// ---------- final: out = sigmoid(logits + b3) ----------
__global__ __launch_bounds__(256) void sigmoid_k(
    const float* __restrict__ lg, const float* __restrict__ b3, float* __restrict__ out) {
  const int i = blockIdx.x * 256 + threadIdx.x;
  out[i] = 1.f / (1.f + __expf(-(lg[i] + b3[0])));
}

// ---------- launcher ----------
extern "C" void kernel_launch(void* const* d_in, const int* in_sizes, int n_in,
                              void* d_out, int out_size, void* d_ws, size_t ws_size,
                              hipStream_t stream) {
  (void)in_sizes; (void)n_in; (void)out_size; (void)ws_size;
  const float* emb1 = (const float*)d_in[0];
  const float* emb2 = (const float*)d_in[1];
  const int*   mask1 = (const int*)d_in[2];
  const int*   mask2 = (const int*)d_in[3];
  const float* Wq = (const float*)d_in[4];  const float* bq = (const float*)d_in[5];
  const float* Wk = (const float*)d_in[6];  const float* bk = (const float*)d_in[7];
  const float* Wv = (const float*)d_in[8];  const float* bv = (const float*)d_in[9];
  const float* W1 = (const float*)d_in[10]; const float* b1 = (const float*)d_in[11];
  const float* W2 = (const float*)d_in[12]; const float* b2 = (const float*)d_in[13];
  const float* W3 = (const float*)d_in[14]; const float* b3 = (const float*)d_in[15];

  // ws layout (bytes), hand-aliased; peak ~185 MiB
  char* ws = (char*)d_ws;
  u16*  XB    = (u16*)(ws + 0);            // [16384][1024] bf16 (live through SC)
  u16*  XM    = (u16*)(ws + 33554432);     // [16384][1024] bf16 (X.M)
  u16*  VT    = (u16*)(ws + 67108864);     // [1024][16384] bf16 (V^T)
  u16*  E     = (u16*)(ws + 100663296);    // [16384][1024] bf16 (exp scores)
  u16*  ATT   = (u16*)(ws + 134217728);    // [16384][1024] bf16 (attended)
  u16*  WvT   = (u16*)(ws + 167772160);    // [1024][1024] bf16
  u16*  Wqb   = (u16*)(ws + 169869312);    // [1024][1024] bf16 (row-major)
  u16*  Wkb   = (u16*)(ws + 171966464);    // [1024][1024] bf16
  u16*  MTb   = (u16*)(ws + 174063616);    // [1024][1024] bf16: MT[n,e]=sum_d Wk[n,d]Wq[e,d]
  u16*  W1T   = (u16*)(ws + 176160768);    // [2048][1024] bf16
  u16*  W2T   = (u16*)(ws + 180355072);    // [1024][2048] bf16
  float* VQ   = (float*)(ws + 184549376);  // [1024] Wq.bk
  float* VK   = (float*)(ws + 184553472);  // [1024] Wk.bq
  float* CC   = (float*)(ws + 184557568);  // [1] bq.bk
  float* U    = (float*)(ws + 184561664);  // [16384] u-vec (+c)
  float* W_   = (float*)(ws + 184627200);  // [16384] w-vec
  float* RS   = (float*)(ws + 184692736);  // [16][1024] rowsums (zeroed per call)
  float* LG   = (float*)(ws + 184758272);  // [16384] logits (zeroed per call)
  u16*  H1    = XB;                        // XB+XM dead after SC -> H1 [16384][2048] @0
  float* out  = (float*)d_out;

  const float SCALE = 0.04419417382415922f;  // 1/sqrt(512)

  hipMemsetAsync(RS, 0, 131072, stream);   // RS (64KB) + LG (64KB), adjacent

  prep<<<10496, 256, 0, stream>>>(emb1, emb2, XB, Wq, Wk, Wv, W1, W2,
                                  Wqb, Wkb, WvT, W1T, W2T);
  bias_vecs<<<513, 256, 0, stream>>>(Wq, Wk, bq, bk, VQ, VK, CC);
  uw_vecs<<<4096, 256, 0, stream>>>(XB, VQ, VK, CC, U, W_);

  // MT[n,e] = sum_d Wk[n,d] Wq[e,d]  (A=Wkb, B=Wqb; both row-major bf16)
  gemm256<0><<<dim3(4, 4, 1), 512, 0, stream>>>(
      Wkb, 1024, 0, Wqb, 1024, 0, MTb, 1024, 0, nullptr, 1.f, 1024,
      nullptr, nullptr, nullptr, nullptr, nullptr, nullptr, nullptr);
  // XM = X . M  (B-operand = MT in [N][K] layout)
  gemm256<0><<<dim3(4, 64, 1), 512, 0, stream>>>(
      XB, 1024, 0, MTb, 1024, 0, XM, 1024, 0, nullptr, 1.f, 1024,
      nullptr, nullptr, nullptr, nullptr, nullptr, nullptr, nullptr);
  // V^T: VT[d, b*S+s] = sum_k WvT[d,k]*XB[b*S+s,k] + bv[d] (row bias)
  gemm256<2><<<dim3(64, 4, 1), 512, 0, stream>>>(
      WvT, 1024, 0, XB, 1024, 0, VT, 16384, 0, bv, 1.f, 1024,
      nullptr, nullptr, nullptr, nullptr, nullptr, nullptr, nullptr);
  // E = exp((XM.X^T + u + w)*scale) masked, + rowsums
  gemm256<3><<<dim3(4, 4, 16), 512, 0, stream>>>(
      XM, 1024, 1048576LL, XB, 1024, 1048576LL,
      E, 1024, 1048576LL, nullptr, SCALE, 1024,
      mask1, mask2, RS, U, W_, nullptr, nullptr);
  // attended = (E @ V) / rowsum
  gemm256<4><<<dim3(4, 4, 16), 512, 0, stream>>>(
      E, 1024, 1048576LL, VT, 16384, 1024LL,
      ATT, 1024, 1048576LL, nullptr, 1.f, 1024,
      nullptr, nullptr, RS, nullptr, nullptr, nullptr, nullptr);
  // MLP1: relu(ATT x W1 + b1) -> H1
  gemm256<1><<<dim3(8, 64, 1), 512, 0, stream>>>(
      ATT, 1024, 0, W1T, 1024, 0, H1, 2048, 0, b1, 1.f, 1024,
      nullptr, nullptr, nullptr, nullptr, nullptr, nullptr, nullptr);
  // MLP2 fused with logits dot: relu(H1 x W2 + b2) . W3 -> LG (no H2 write)
  gemm256<5><<<dim3(4, 64, 1), 512, 0, stream>>>(
      H1, 2048, 0, W2T, 2048, 0, nullptr, 1024, 0, b2, 1.f, 2048,
      nullptr, nullptr, nullptr, nullptr, nullptr, W3, LG);
  sigmoid_k<<<64, 256, 0, stream>>>(LG, b3, out);
}

// Round 15
// 354.349 us; speedup vs baseline: 1.0386x; 1.0386x over previous
//
#include <hip/hip_runtime.h>
#include <math.h>

#define DEV __device__ __forceinline__
#define SB0() __builtin_amdgcn_sched_barrier(0)

typedef unsigned short u16;
typedef unsigned int   u32;
typedef __bf16 bf16x8 __attribute__((ext_vector_type(8)));
typedef float  f32x4  __attribute__((ext_vector_type(4)));
typedef u16    u16x8  __attribute__((ext_vector_type(8)));

// ---------- helpers ----------
DEV u16 f2b(float f) {                 // f32 -> bf16 RNE
  u32 u = __builtin_bit_cast(u32, f);
  u = (u + 0x7FFFu + ((u >> 16) & 1u)) >> 16;
  return (u16)u;
}
DEV float b2f(u16 h) { u32 u = (u32)h << 16; return __builtin_bit_cast(float, u); }

DEV void gl_lds16(const u16* g, u16* l) {  // async global->LDS, 16B/lane (lds ptr wave-uniform)
  __builtin_amdgcn_global_load_lds((const __attribute__((address_space(1))) void*)g,
                                   (__attribute__((address_space(3))) void*)l, 16, 0, 0);
}

// ============================================================================
// Fused prep (r9-verified): concat/convert, 5 weight transposes, bias concat.
// ============================================================================
__global__ __launch_bounds__(256) void prep(
    const float* __restrict__ e1, const float* __restrict__ e2, u16* __restrict__ xb,
    const float* __restrict__ Wq, const float* __restrict__ Wk, const float* __restrict__ Wv,
    const float* __restrict__ W1, const float* __restrict__ W2,
    u16* __restrict__ WTQKV, u16* __restrict__ W1T, u16* __restrict__ W2T,
    const float* __restrict__ bq, const float* __restrict__ bk, float* __restrict__ bf) {
  __shared__ float tile[64][65];
  const int bid = blockIdx.x;
  if (bid < 8192) {                       // concat+convert
    const size_t idx = ((size_t)bid * 256 + threadIdx.x) * 8;
    const int d = (int)(idx & 1023);
    const size_t row = idx >> 10;
    const float* s = (d < 512) ? (e1 + row * 512 + d) : (e2 + row * 512 + (d - 512));
    f32x4 a = *(const f32x4*)s;
    f32x4 b = *(const f32x4*)(s + 4);
    u16x8 o;
    o[0]=f2b(a[0]); o[1]=f2b(a[1]); o[2]=f2b(a[2]); o[3]=f2b(a[3]);
    o[4]=f2b(b[0]); o[5]=f2b(b[1]); o[6]=f2b(b[2]); o[7]=f2b(b[3]);
    *(u16x8*)(xb + idx) = o;
    return;
  }
  if (bid >= 9984) {                      // bias concat
    int i = (bid - 9984) * 256 + threadIdx.x;
    bf[i] = (i < 1024) ? bq[i] : bk[i - 1024];
    return;
  }
  const float* W; u16* WT; int ldi, ldo, bx, by;
  if (bid < 8448)      { W = Wq; WT = WTQKV;              ldi = 1024; ldo = 1024; int v = bid - 8192; bx = v & 15; by = v >> 4; }
  else if (bid < 8704) { W = Wk; WT = WTQKV + 1024*1024;  ldi = 1024; ldo = 1024; int v = bid - 8448; bx = v & 15; by = v >> 4; }
  else if (bid < 8960) { W = Wv; WT = WTQKV + 2048*1024;  ldi = 1024; ldo = 1024; int v = bid - 8704; bx = v & 15; by = v >> 4; }
  else if (bid < 9472) { W = W1; WT = W1T;                ldi = 2048; ldo = 1024; int v = bid - 8960; bx = v & 31; by = v >> 5; }
  else                 { W = W2; WT = W2T;                ldi = 1024; ldo = 2048; int v = bid - 9472; bx = v & 15; by = v >> 4; }
  const int tx = threadIdx.x & 63, ty = threadIdx.x >> 6;
  const int r0 = by * 64, c0 = bx * 64;
#pragma unroll
  for (int i = 0; i < 16; ++i)
    tile[ty + 4*i][tx] = W[(size_t)(r0 + ty + 4*i) * ldi + c0 + tx];
  __syncthreads();
#pragma unroll
  for (int i = 0; i < 16; ++i)
    WT[(size_t)(c0 + ty + 4*i) * ldo + r0 + tx] = f2b(tile[tx][ty + 4*i]);
}

// ============================================================================
// 8-phase 256x256 template (r11, best verified: 348.6us total). MODE epilogues:
//  0 col-bias | 1 col-bias+relu | 2 row-bias | 3 exp+mask+atomic-rowsum |
//  4 x(1/rowsum) | 5 bias+relu+dot(W3)+atomic logits (no C write).
// Coalesced bf16 LDS-bounce store (r9-verified WRITE_SIZE == logical).
// ============================================================================
template<int MODE>
__global__ __launch_bounds__(512, 2) void gemm256(
    const u16* __restrict__ A, int lda, long long sA,
    const u16* __restrict__ B, int ldb, long long sB,
    void* __restrict__ C, int ldc, long long sC,
    const float* __restrict__ bias, float scale, int K,
    const int* __restrict__ mk1, const int* __restrict__ mk2,
    float* __restrict__ rsw, const float* __restrict__ w3, float* __restrict__ lg) {
  __shared__ __align__(16) u16 lds[2][2][16384];  // [buf][A/B][2half x 128r x 64c]

  const int t  = threadIdx.x;
  const int ln = t & 63, wv = t >> 6;

  // --- 2D-chunked bijective XCD swizzle (all grids have nwg % 8 == 0) ---
  int bx, by, bz;
  {
    const int gx = gridDim.x, gy = gridDim.y, gz = gridDim.z;
    const int nwg = gx * gy * gz;
    const int F = (blockIdx.z * gy + blockIdx.y) * gx + blockIdx.x;
    const int q = nwg >> 3;
    const int L = (F & 7) * q + (F >> 3);        // XCD k executes L in [k*q,(k+1)*q)
    if (gz > 1) {
      const int pb = gx * gy;
      bz = L / pb; const int r = L - bz * pb;
      by = r / gx; bx = r - by * gx;             // batch-major: whole batches per XCD
    } else {
      bz = 0;
      const int sh = ((gy & 7) == 0) ? 8 : 4;    // slab height (gy=64 or gy=4)
      const int sw = gx * sh;
      const int sy = L / sw; const int r = L - sy * sw;
      bx = r / sh; by = sy * sh + (r - bx * sh); // slab-major: A-slab resident per XCD
    }
  }
  const int m0 = by * 256, n0 = bx * 256;
  A += (size_t)bz * (size_t)sA; B += (size_t)bz * (size_t)sB;

  // staging bases: thread t covers (row t>>3, phys granule t&7) of a half-tile;
  // pre-swizzled logical granule gl = (ln&7) ^ (ln>>3)
  const int gl = (ln & 7) ^ (ln >> 3);
  const u16* gAs = A + (size_t)(m0 + (t >> 3)) * lda + gl * 8;
  const u16* gBs = B + (size_t)(n0 + (t >> 3)) * ldb + gl * 8;

  // read constants
  const int l15 = ln & 15, lhi = ln >> 4;
  const int wm = (wv >> 2) * 128, wn = (wv & 3) * 64;
  const int colk0 = ((lhi ^ (l15 & 7)) << 3);          // kslot 0 swizzled col (elems)
  const int colk1 = (((4 + lhi) ^ (l15 & 7)) << 3);    // kslot 1
  const int rcA = (wv >> 2) * 8192 + l15 * 64;         // A half + row base
  const int rcB = ((wv & 3) >> 1) * 8192 + (wv & 1) * 4096 + l15 * 64;

  f32x4 acc[8][4] = {};
  bf16x8 Af[4][2], Bf[4][2];
  const int KT = K >> 6, NIT = KT >> 1;

#define STG(T, OP, H, LD, GS)                                              \
  if ((T) < KT) {                                                          \
    const u16* _s = (GS) + (size_t)(H) * 128 * (size_t)(LD) + (size_t)(T) * 64; \
    u16* _d = &lds[(T) & 1][OP][(H) * 8192 + wv * 512];                    \
    gl_lds16(_s, _d); gl_lds16(_s + 64 * (size_t)(LD), _d + 4096);         \
  }
#define RDA(BUF, ILO) {                                                    \
  _Pragma("unroll") for (int ii = 0; ii < 4; ++ii) {                       \
    Af[ii][0] = *(const bf16x8*)&lds[BUF][0][rcA + ((ILO) + ii) * 1024 + colk0]; \
    Af[ii][1] = *(const bf16x8*)&lds[BUF][0][rcA + ((ILO) + ii) * 1024 + colk1]; } }
#define RDB(BUF, JLO) {                                                    \
  _Pragma("unroll") for (int jj = 0; jj < 2; ++jj) {                       \
    Bf[(JLO) + jj][0] = *(const bf16x8*)&lds[BUF][1][rcB + ((JLO) + jj) * 1024 + colk0]; \
    Bf[(JLO) + jj][1] = *(const bf16x8*)&lds[BUF][1][rcB + ((JLO) + jj) * 1024 + colk1]; } }
#define MM(ILO, JLO) {                                                     \
  _Pragma("unroll") for (int ii = 0; ii < 4; ++ii)                         \
  _Pragma("unroll") for (int jj = 0; jj < 2; ++jj) {                       \
    acc[(ILO)+ii][(JLO)+jj] = __builtin_amdgcn_mfma_f32_16x16x32_bf16(Af[ii][0], Bf[(JLO)+jj][0], acc[(ILO)+ii][(JLO)+jj], 0, 0, 0); \
    acc[(ILO)+ii][(JLO)+jj] = __builtin_amdgcn_mfma_f32_16x16x32_bf16(Af[ii][1], Bf[(JLO)+jj][1], acc[(ILO)+ii][(JLO)+jj], 0, 0, 0); } }
#define BAR() __builtin_amdgcn_s_barrier()
#define PRIO(x) __builtin_amdgcn_s_setprio(x)

  // prologue: T0 all 4 halves + T1's B halves; vmcnt(4) -> T0 landed
  STG(0, 0, 0, lda, gAs); STG(0, 0, 1, lda, gAs);
  STG(0, 1, 0, ldb, gBs); STG(0, 1, 1, ldb, gBs);
  STG(1, 1, 0, ldb, gBs); STG(1, 1, 1, ldb, gBs);
  asm volatile("s_waitcnt vmcnt(4)" ::: "memory");
  SB0(); BAR();

  for (int it = 0; it < NIT; ++it) {
    const int T0 = it << 1, T1 = T0 + 1;
    // ---- P1: Q0 of T0 ----
    RDB(0, 0); RDA(0, 0); STG(T1, 0, 0, lda, gAs);
    BAR();
    PRIO(1); MM(0, 0); PRIO(0); BAR();
    // ---- P2: Q1 of T0 ----
    RDB(0, 2); STG(T1, 0, 1, lda, gAs);
    BAR();
    PRIO(1); MM(0, 2); PRIO(0); BAR();
    // ---- P3: Q2 of T0 ----
    RDA(0, 4); STG(T0 + 2, 1, 0, ldb, gBs);
    BAR();
    PRIO(1); MM(4, 0); PRIO(0); BAR();
    // ---- P4: Q3 of T0 + counted vmcnt ----
    STG(T0 + 2, 1, 1, ldb, gBs);
    BAR();
    PRIO(1); MM(4, 2); PRIO(0);
    if (T0 + 2 < KT) { asm volatile("s_waitcnt vmcnt(4)" ::: "memory"); }
    else             { asm volatile("s_waitcnt vmcnt(0)" ::: "memory"); }
    SB0(); BAR();
    // ---- P5: Q0 of T1 ----
    RDB(1, 0); RDA(1, 0); STG(T0 + 2, 0, 0, lda, gAs);
    BAR();
    PRIO(1); MM(0, 0); PRIO(0); BAR();
    // ---- P6: Q1 of T1 ----
    RDB(1, 2); STG(T0 + 2, 0, 1, lda, gAs);
    BAR();
    PRIO(1); MM(0, 2); PRIO(0); BAR();
    // ---- P7: Q2 of T1 ----
    RDA(1, 4); STG(T0 + 3, 1, 0, ldb, gBs);
    BAR();
    PRIO(1); MM(4, 0); PRIO(0); BAR();
    // ---- P8: Q3 of T1 + counted vmcnt ----
    STG(T0 + 3, 1, 1, ldb, gBs);
    BAR();
    PRIO(1); MM(4, 2); PRIO(0);
    if (T0 + 3 < KT) { asm volatile("s_waitcnt vmcnt(4)" ::: "memory"); }
    SB0(); BAR();
  }
#undef STG
#undef RDA
#undef RDB
#undef MM
#undef BAR
#undef PRIO

  // ---------------- epilogue (frag D row=(lhi*4+r), col=l15; m89-verified) ----------------
  const size_t cb = (size_t)bz * (size_t)sC;

  if (MODE == 5) {
    float w3v[4];
#pragma unroll
    for (int j = 0; j < 4; ++j) w3v[j] = w3[n0 + wn + j * 16 + l15];
#pragma unroll
    for (int i = 0; i < 8; ++i) {
      const int rg = m0 + wm + i * 16 + lhi * 4;
#pragma unroll
      for (int r = 0; r < 4; ++r) {
        float s = 0.f;
#pragma unroll
        for (int j = 0; j < 4; ++j) {
          float v = acc[i][j][r] + bias[n0 + wn + j * 16 + l15];
          v = fmaxf(v, 0.f);
          s += v * w3v[j];
        }
        s += __shfl_xor(s, 1, 64); s += __shfl_xor(s, 2, 64);
        s += __shfl_xor(s, 4, 64); s += __shfl_xor(s, 8, 64);
        if (l15 == 0) atomicAdd(&lg[rg + r], s);
      }
    }
    return;
  }

  u16* ep = ((u16*)lds) + wv * 8192;  // [128 rows][64 cols] wave-private bounce

  if (MODE == 3) {
#pragma unroll
    for (int i = 0; i < 8; ++i) {
#pragma unroll
      for (int r = 0; r < 4; ++r) {
        const int rr = m0 + wm + i * 16 + lhi * 4 + r;      // row in [0,1024)
        const int mk = (rr < 512) ? mk1[bz * 512 + rr] : mk2[bz * 512 + rr - 512];
        const int lrow = i * 16 + lhi * 4 + r;
        float s = 0.f;
#pragma unroll
        for (int j = 0; j < 4; ++j) {
          float e = (mk != 0) ? __expf(acc[i][j][r] * scale) : 0.f;
          const u16 eb = f2b(e);
          s += b2f(eb);
          const int lcol = (j * 16 + l15) ^ (((lrow >> 2) & 7) << 3);
          ep[lrow * 64 + lcol] = eb;
        }
        s += __shfl_xor(s, 1, 64); s += __shfl_xor(s, 2, 64);
        s += __shfl_xor(s, 4, 64); s += __shfl_xor(s, 8, 64);
        if (l15 == 0) atomicAdd(&rsw[(size_t)bz * 1024 + rr], s);
      }
    }
  } else {
#pragma unroll
    for (int i = 0; i < 8; ++i) {
      const int rl = wm + i * 16 + lhi * 4;
      float rv[4];
#pragma unroll
      for (int r = 0; r < 4; ++r) {
        if (MODE == 2)      rv[r] = bias[m0 + rl + r];
        else if (MODE == 4) rv[r] = 1.f / rsw[(size_t)bz * 1024 + m0 + rl + r];
        else                rv[r] = 0.f;
      }
#pragma unroll
      for (int j = 0; j < 4; ++j) {
        const float cbv = (MODE == 0 || MODE == 1) ? bias[n0 + wn + j * 16 + l15] : 0.f;
#pragma unroll
        for (int r = 0; r < 4; ++r) {
          float v;
          if (MODE == 4)      v = acc[i][j][r] * rv[r];
          else if (MODE == 2) v = acc[i][j][r] + rv[r];
          else                v = acc[i][j][r] + cbv;
          if (MODE == 1) v = fmaxf(v, 0.f);
          const int lrow = i * 16 + lhi * 4 + r;
          const int lcol = (j * 16 + l15) ^ (((lrow >> 2) & 7) << 3);
          ep[lrow * 64 + lcol] = f2b(v);
        }
      }
    }
  }
  asm volatile("s_waitcnt lgkmcnt(0)" ::: "memory");  // own bounce writes landed
  SB0();
  const int l3 = ln >> 3, c0 = (ln & 7) * 8;
#pragma unroll
  for (int rep = 0; rep < 16; ++rep) {
    const int lr = rep * 8 + l3;
    const int cs = c0 ^ (((lr >> 2) & 7) << 3);
    u16x8 v = *(const u16x8*)&ep[lr * 64 + cs];
    *(u16x8*)((u16*)C + cb + (size_t)(m0 + wm + lr) * ldc + n0 + wn + c0) = v;
  }
}

// ============================================================================
// r13 128x256 2-block/CU template — measured faster for the two 2-round
// dispatches (QK, MLP1: 77-79.5us vs gemm256's 81.4-82.1us, r13 vs r11 data).
// BM=128 x BN=256, 8 waves 2Mx4N, wave 64x64, BK=32, ring-3 counted vmcnt,
// LDS 72KB -> 2 blocks/CU. Verified end-to-end in r13 (passed, absmax 3.9e-3).
// Only MODE 0 (col-bias) and MODE 1 (col-bias+relu) are instantiated here.
// ============================================================================
template<int MODE>
__global__ __launch_bounds__(512, 4) void gemm128(
    const u16* __restrict__ A, int lda,
    const u16* __restrict__ B, int ldb,
    void* __restrict__ C, int ldc,
    const float* __restrict__ bias, int K) {
  __shared__ __align__(16) u16 lds[3 * 12288];  // ring of {A 4096, B 8192} | bounce 8x4096

  const int t  = threadIdx.x;
  const int ln = t & 63, wv = t >> 6;

  // --- 2D-chunked bijective XCD swizzle (gz==1, gy%8==0) ---
  int bx, by;
  {
    const int gx = gridDim.x, gy = gridDim.y;
    const int nwg = gx * gy;
    const int F = blockIdx.y * gx + blockIdx.x;
    const int q = nwg >> 3;
    const int L = (F & 7) * q + (F >> 3);
    const int sw = gx * 8;
    const int sy = L / sw; const int r = L - sy * sw;
    bx = r >> 3; by = sy * 8 + (r & 7);          // A-slab L2-resident per XCD
  }
  const int m0 = by * 128, n0 = bx * 256;

  // staging: thread t -> row t>>2, phys granule t&3; pre-swizzled source
  // granule = (t&3) ^ ((t>>3)&3)
  const int srow = t >> 2;                       // 0..127
  const int sg   = (t & 3) ^ ((t >> 3) & 3);
  const u16* gA = A + (size_t)(m0 + srow) * lda + sg * 8;
  const u16* gB = B + (size_t)(n0 + srow) * ldb + sg * 8;   // rows +0 and +128
  const size_t b128r = (size_t)128 * ldb;
  const int ldst = wv * 512;

  const int l15 = ln & 15, lhi = ln >> 4;
  const int wm = (wv >> 2) * 64, wn = (wv & 3) * 64;

  int offA[4], offB[4];
#pragma unroll
  for (int i = 0; i < 4; ++i) {
    const int r = wm + i * 16 + l15;
    offA[i] = r * 32 + ((lhi ^ ((r >> 1) & 3)) << 3);
  }
#pragma unroll
  for (int j = 0; j < 4; ++j) {
    const int r = wn + j * 16 + l15;
    offB[j] = 4096 + r * 32 + ((lhi ^ ((r >> 1) & 3)) << 3);
  }

  f32x4 acc[4][4] = {};
  const int KT = K >> 5;

#define STAGE(T, RB)                                                      \
  {                                                                       \
    const u16* _a = gA + (size_t)(T) * 32;                                \
    const u16* _b = gB + (size_t)(T) * 32;                                \
    gl_lds16(_a, &lds[(RB) * 12288 + ldst]);                              \
    gl_lds16(_b, &lds[(RB) * 12288 + 4096 + ldst]);                       \
    gl_lds16(_b + b128r, &lds[(RB) * 12288 + 8192 + ldst]);               \
  }
#define MF(i, j, Av, Bv) \
  acc[i][j] = __builtin_amdgcn_mfma_f32_16x16x32_bf16(Av, Bv, acc[i][j], 0, 0, 0)

  STAGE(0, 0); STAGE(1, 1);
  asm volatile("s_waitcnt vmcnt(3)" ::: "memory");
  SB0();
  __builtin_amdgcn_s_barrier();

  int rb_read = 0, rb_stage = 2;
  for (int kt = 0; kt < KT; ++kt) {
    if (kt + 2 < KT) STAGE(kt + 2, rb_stage);
    const u16* bb = &lds[rb_read * 12288];
    bf16x8 a0 = *(const bf16x8*)&bb[offA[0]];
    bf16x8 a1 = *(const bf16x8*)&bb[offA[1]];
    bf16x8 a2 = *(const bf16x8*)&bb[offA[2]];
    bf16x8 a3 = *(const bf16x8*)&bb[offA[3]];
    bf16x8 b0 = *(const bf16x8*)&bb[offB[0]];
    bf16x8 b1 = *(const bf16x8*)&bb[offB[1]];
    bf16x8 b2 = *(const bf16x8*)&bb[offB[2]];
    bf16x8 b3 = *(const bf16x8*)&bb[offB[3]];
    __builtin_amdgcn_s_setprio(1);
    MF(0,0,a0,b0); MF(0,1,a0,b1); MF(0,2,a0,b2); MF(0,3,a0,b3);
    MF(1,0,a1,b0); MF(1,1,a1,b1); MF(1,2,a1,b2); MF(1,3,a1,b3);
    MF(2,0,a2,b0); MF(2,1,a2,b1); MF(2,2,a2,b2); MF(2,3,a2,b3);
    MF(3,0,a3,b0); MF(3,1,a3,b1); MF(3,2,a3,b2); MF(3,3,a3,b3);
    __builtin_amdgcn_s_setprio(0);
    if (kt < KT - 2)       { asm volatile("s_waitcnt vmcnt(3)" ::: "memory"); }
    else if (kt == KT - 2) { asm volatile("s_waitcnt vmcnt(0)" ::: "memory"); }
    if (kt < KT - 1) {
      SB0();
      __builtin_amdgcn_s_barrier();
    }
    rb_read  = (rb_read  == 2) ? 0 : rb_read + 1;
    rb_stage = (rb_stage == 2) ? 0 : rb_stage + 1;
  }
#undef STAGE
#undef MF

  // epilogue: bf16 LDS-bounce coalesced store (r13-verified)
  u16* ep = lds + wv * 4096;  // [64 rows][64 cols] wave-private
#pragma unroll
  for (int i = 0; i < 4; ++i) {
#pragma unroll
    for (int j = 0; j < 4; ++j) {
      const float cbv = bias[n0 + wn + j * 16 + l15];
#pragma unroll
      for (int r = 0; r < 4; ++r) {
        float v = acc[i][j][r] + cbv;
        if (MODE == 1) v = fmaxf(v, 0.f);
        const int lrow = i * 16 + lhi * 4 + r;
        const int lcol = (j * 16 + l15) ^ (((lrow >> 2) & 7) << 3);
        ep[lrow * 64 + lcol] = f2b(v);
      }
    }
  }
  asm volatile("s_waitcnt lgkmcnt(0)" ::: "memory");
  SB0();
  const int l3 = ln >> 3, c0 = (ln & 7) * 8;
#pragma unroll
  for (int rep = 0; rep < 8; ++rep) {
    const int lr = rep * 8 + l3;
    const int cs = c0 ^ (((lr >> 2) & 7) << 3);
    u16x8 v = *(const u16x8*)&ep[lr * 64 + cs];
    *(u16x8*)((u16*)C + (size_t)(m0 + wm + lr) * ldc + n0 + wn + c0) = v;
  }
}

// ---------- final: out = sigmoid(logits + b3) ----------
__global__ __launch_bounds__(256) void sigmoid_k(
    const float* __restrict__ lg, const float* __restrict__ b3, float* __restrict__ out) {
  const int i = blockIdx.x * 256 + threadIdx.x;
  out[i] = 1.f / (1.f + __expf(-(lg[i] + b3[0])));
}

// ---------- launcher ----------
extern "C" void kernel_launch(void* const* d_in, const int* in_sizes, int n_in,
                              void* d_out, int out_size, void* d_ws, size_t ws_size,
                              hipStream_t stream) {
  (void)in_sizes; (void)n_in; (void)out_size; (void)ws_size;
  const float* emb1 = (const float*)d_in[0];
  const float* emb2 = (const float*)d_in[1];
  const int*   mask1 = (const int*)d_in[2];
  const int*   mask2 = (const int*)d_in[3];
  const float* Wq = (const float*)d_in[4];  const float* bq = (const float*)d_in[5];
  const float* Wk = (const float*)d_in[6];  const float* bk = (const float*)d_in[7];
  const float* Wv = (const float*)d_in[8];  const float* bv = (const float*)d_in[9];
  const float* W1 = (const float*)d_in[10]; const float* b1 = (const float*)d_in[11];
  const float* W2 = (const float*)d_in[12]; const float* b2 = (const float*)d_in[13];
  const float* W3 = (const float*)d_in[14]; const float* b3 = (const float*)d_in[15];

  // ws layout (bytes), hand-aliased; peak ~183 MiB
  char* ws = (char*)d_ws;
  u16*  XB    = (u16*)(ws + 0);            // [16384][1024] bf16; later E (scores exp)
  u16*  QK    = (u16*)(ws + 33554432);     // [16384][2048] bf16 (Q|K); later H1
  u16*  VT    = (u16*)(ws + 100663296);    // [1024][16384] bf16 (V^T)
  u16*  ATT   = (u16*)(ws + 134217728);    // [16384][1024] bf16 (attended)
  u16*  WTQKV = (u16*)(ws + 167772160);    // [3072][1024] bf16
  u16*  W1T   = (u16*)(ws + 174063616);    // [2048][1024] bf16
  u16*  W2T   = (u16*)(ws + 178257920);    // [1024][2048] bf16
  float* BF_  = (float*)(ws + 182452224);  // [2048] f32 (bq|bk)
  float* RS   = (float*)(ws + 182460416);  // [16][1024] f32 rowsums (zeroed per call)
  float* LG   = (float*)(ws + 182525952);  // [16384] f32 logits (zeroed per call)
  u16*  E     = XB;                        // XB dead after V-GEMM
  u16*  H1    = QK;                        // QK dead after scores GEMM
  float* out  = (float*)d_out;

  const float SCALE = 0.04419417382415922f;  // 1/sqrt(512)

  hipMemsetAsync(RS, 0, 131072, stream);   // RS (64KB) + LG (64KB), adjacent

  prep<<<9992, 256, 0, stream>>>(emb1, emb2, XB, Wq, Wk, Wv, W1, W2,
                                 WTQKV, W1T, W2T, bq, bk, BF_);

  // Q|K: [16384,1024] x [1024,2048]^T-layout -> bf16 [16384,2048]  (r13 kernel)
  gemm128<0><<<dim3(8, 128, 1), 512, 0, stream>>>(
      XB, 1024, WTQKV, 1024, QK, 2048, BF_, 1024);
  // V^T: VT[d, b*S+s] = sum_k WvT[d,k]*XB[b*S+s,k] + bv[d] (row bias)
  gemm256<2><<<dim3(64, 4, 1), 512, 0, stream>>>(
      WTQKV + 2048 * 1024, 1024, 0, XB, 1024, 0, VT, 16384, 0, bv, 1.f, 1024,
      nullptr, nullptr, nullptr, nullptr, nullptr);
  // E = exp(scale * Q K^T) masked, + rowsums (softmax fused; no max pass)
  gemm256<3><<<dim3(4, 4, 16), 512, 0, stream>>>(
      QK, 2048, 2097152LL, QK + 1024, 2048, 2097152LL,
      E, 1024, 1048576LL, nullptr, SCALE, 1024,
      mask1, mask2, RS, nullptr, nullptr);
  // attended = (E @ V) / rowsum
  gemm256<4><<<dim3(4, 4, 16), 512, 0, stream>>>(
      E, 1024, 1048576LL, VT, 16384, 1024LL,
      ATT, 1024, 1048576LL, nullptr, 1.f, 1024,
      nullptr, nullptr, RS, nullptr, nullptr);
  // MLP1: relu(ATT x W1 + b1) -> H1  (r13 kernel)
  gemm128<1><<<dim3(8, 128, 1), 512, 0, stream>>>(
      ATT, 1024, W1T, 1024, H1, 2048, b1, 1024);
  // MLP2 fused with logits dot: relu(H1 x W2 + b2) . W3 -> LG (no H2 write)
  gemm256<5><<<dim3(4, 64, 1), 512, 0, stream>>>(
      H1, 2048, 0, W2T, 2048, 0, nullptr, 1024, 0, b2, 1.f, 2048,
      nullptr, nullptr, nullptr, W3, LG);
  sigmoid_k<<<64, 256, 0, stream>>>(LG, b3, out);
}

// Round 16
// 352.101 us; speedup vs baseline: 1.0452x; 1.0064x over previous
//
#include <hip/hip_runtime.h>
#include <math.h>

#define DEV __device__ __forceinline__
#define SB0() __builtin_amdgcn_sched_barrier(0)

typedef unsigned short u16;
typedef unsigned int   u32;
typedef __bf16 bf16x8 __attribute__((ext_vector_type(8)));
typedef float  f32x4  __attribute__((ext_vector_type(4)));
typedef u16    u16x8  __attribute__((ext_vector_type(8)));

// ---------- helpers ----------
DEV u16 f2b(float f) {                 // f32 -> bf16 RNE
  u32 u = __builtin_bit_cast(u32, f);
  u = (u + 0x7FFFu + ((u >> 16) & 1u)) >> 16;
  return (u16)u;
}
DEV float b2f(u16 h) { u32 u = (u32)h << 16; return __builtin_bit_cast(float, u); }

DEV void gl_lds16(const u16* g, u16* l) {  // async global->LDS, 16B/lane (lds ptr wave-uniform)
  __builtin_amdgcn_global_load_lds((const __attribute__((address_space(1))) void*)g,
                                   (__attribute__((address_space(3))) void*)l, 16, 0, 0);
}

// ============================================================================
// Fused prep: blockIdx ranges ->
//  [0,8192)      concat emb1|emb2 -> bf16 XB
//  [8192,8448)   Wq^T   [8448,8704) Wk^T   [8704,8960) Wv^T   (1024x1024)
//  [8960,9472)   W1^T (1024x2048 -> 2048x1024)
//  [9472,9984)   W2^T (2048x1024 -> 1024x2048)
//  [9984,9992)   bias concat bq|bk
// ============================================================================
__global__ __launch_bounds__(256) void prep(
    const float* __restrict__ e1, const float* __restrict__ e2, u16* __restrict__ xb,
    const float* __restrict__ Wq, const float* __restrict__ Wk, const float* __restrict__ Wv,
    const float* __restrict__ W1, const float* __restrict__ W2,
    u16* __restrict__ WTQKV, u16* __restrict__ W1T, u16* __restrict__ W2T,
    const float* __restrict__ bq, const float* __restrict__ bk, float* __restrict__ bf) {
  __shared__ float tile[64][65];
  const int bid = blockIdx.x;
  if (bid < 8192) {                       // concat+convert
    const size_t idx = ((size_t)bid * 256 + threadIdx.x) * 8;
    const int d = (int)(idx & 1023);
    const size_t row = idx >> 10;
    const float* s = (d < 512) ? (e1 + row * 512 + d) : (e2 + row * 512 + (d - 512));
    f32x4 a = *(const f32x4*)s;
    f32x4 b = *(const f32x4*)(s + 4);
    u16x8 o;
    o[0]=f2b(a[0]); o[1]=f2b(a[1]); o[2]=f2b(a[2]); o[3]=f2b(a[3]);
    o[4]=f2b(b[0]); o[5]=f2b(b[1]); o[6]=f2b(b[2]); o[7]=f2b(b[3]);
    *(u16x8*)(xb + idx) = o;
    return;
  }
  if (bid >= 9984) {                      // bias concat
    int i = (bid - 9984) * 256 + threadIdx.x;
    bf[i] = (i < 1024) ? bq[i] : bk[i - 1024];
    return;
  }
  // weight transposes
  const float* W; u16* WT; int ldi, ldo, bx, by;
  if (bid < 8448)      { W = Wq; WT = WTQKV;              ldi = 1024; ldo = 1024; int v = bid - 8192; bx = v & 15; by = v >> 4; }
  else if (bid < 8704) { W = Wk; WT = WTQKV + 1024*1024;  ldi = 1024; ldo = 1024; int v = bid - 8448; bx = v & 15; by = v >> 4; }
  else if (bid < 8960) { W = Wv; WT = WTQKV + 2048*1024;  ldi = 1024; ldo = 1024; int v = bid - 8704; bx = v & 15; by = v >> 4; }
  else if (bid < 9472) { W = W1; WT = W1T;                ldi = 2048; ldo = 1024; int v = bid - 8960; bx = v & 31; by = v >> 5; }
  else                 { W = W2; WT = W2T;                ldi = 1024; ldo = 2048; int v = bid - 9472; bx = v & 15; by = v >> 4; }
  const int tx = threadIdx.x & 63, ty = threadIdx.x >> 6;
  const int r0 = by * 64, c0 = bx * 64;
#pragma unroll
  for (int i = 0; i < 16; ++i)
    tile[ty + 4*i][tx] = W[(size_t)(r0 + ty + 4*i) * ldi + c0 + tx];
  __syncthreads();
#pragma unroll
  for (int i = 0; i < 16; ++i)
    WT[(size_t)(c0 + ty + 4*i) * ldo + r0 + tx] = f2b(tile[tx][ty + 4*i]);
}

// ============================================================================
// 8-phase 256x256 template (r11 configuration — best verified, 348.6us).
// MODE-fused epilogues:
//  MODE 0: bf16 out, col bias            (QK GEMM)
//  MODE 1: bf16 out, col bias + relu     (MLP1)
//  MODE 2: bf16 out, ROW bias            (V^T GEMM)
//  MODE 3: bf16 E=exp(scale*acc) masked + per-row atomic rowsum  (scores)
//  MODE 4: bf16 out, multiply by 1/rowsum[row]   (PV -> attended)
//  MODE 5: NO C write: bias+relu, dot with W3, atomicAdd into logits (MLP2)
// Coalesced bf16 LDS-bounce store (r9-verified WRITE_SIZE == logical).
// ============================================================================
template<int MODE>
__global__ __launch_bounds__(512, 2) void gemm256(
    const u16* __restrict__ A, int lda, long long sA,
    const u16* __restrict__ B, int ldb, long long sB,
    void* __restrict__ C, int ldc, long long sC,
    const float* __restrict__ bias, float scale, int K,
    const int* __restrict__ mk1, const int* __restrict__ mk2,
    float* __restrict__ rsw, const float* __restrict__ w3, float* __restrict__ lg) {
  __shared__ __align__(16) u16 lds[2][2][16384];  // [buf][A/B][2half x 128r x 64c]

  const int t  = threadIdx.x;
  const int ln = t & 63, wv = t >> 6;

  // --- 2D-chunked bijective XCD swizzle (all grids have nwg % 8 == 0) ---
  int bx, by, bz;
  {
    const int gx = gridDim.x, gy = gridDim.y, gz = gridDim.z;
    const int nwg = gx * gy * gz;
    const int F = (blockIdx.z * gy + blockIdx.y) * gx + blockIdx.x;
    const int q = nwg >> 3;
    const int L = (F & 7) * q + (F >> 3);        // XCD k executes L in [k*q,(k+1)*q)
    if (gz > 1) {
      const int pb = gx * gy;
      bz = L / pb; const int r = L - bz * pb;
      by = r / gx; bx = r - by * gx;             // batch-major: whole batches per XCD
    } else {
      bz = 0;
      const int sh = ((gy & 7) == 0) ? 8 : 4;    // slab height (gy=64 or gy=4)
      const int sw = gx * sh;
      const int sy = L / sw; const int r = L - sy * sw;
      bx = r / sh; by = sy * sh + (r - bx * sh); // slab-major: A-slab resident per XCD
    }
  }
  const int m0 = by * 256, n0 = bx * 256;
  A += (size_t)bz * (size_t)sA; B += (size_t)bz * (size_t)sB;

  // staging bases: thread t covers (row t>>3, phys granule t&7) of a half-tile;
  // pre-swizzled logical granule gl = (ln&7) ^ (ln>>3)
  const int gl = (ln & 7) ^ (ln >> 3);
  const u16* gAs = A + (size_t)(m0 + (t >> 3)) * lda + gl * 8;
  const u16* gBs = B + (size_t)(n0 + (t >> 3)) * ldb + gl * 8;

  // read constants
  const int l15 = ln & 15, lhi = ln >> 4;
  const int wm = (wv >> 2) * 128, wn = (wv & 3) * 64;
  const int colk0 = ((lhi ^ (l15 & 7)) << 3);          // kslot 0 swizzled col (elems)
  const int colk1 = (((4 + lhi) ^ (l15 & 7)) << 3);    // kslot 1
  const int rcA = (wv >> 2) * 8192 + l15 * 64;         // A half + row base
  const int rcB = ((wv & 3) >> 1) * 8192 + (wv & 1) * 4096 + l15 * 64;

  f32x4 acc[8][4] = {};
  bf16x8 Af[4][2], Bf[4][2];
  const int KT = K >> 6, NIT = KT >> 1;

#define STG(T, OP, H, LD, GS)                                              \
  if ((T) < KT) {                                                          \
    const u16* _s = (GS) + (size_t)(H) * 128 * (size_t)(LD) + (size_t)(T) * 64; \
    u16* _d = &lds[(T) & 1][OP][(H) * 8192 + wv * 512];                    \
    gl_lds16(_s, _d); gl_lds16(_s + 64 * (size_t)(LD), _d + 4096);         \
  }
#define RDA(BUF, ILO) {                                                    \
  _Pragma("unroll") for (int ii = 0; ii < 4; ++ii) {                       \
    Af[ii][0] = *(const bf16x8*)&lds[BUF][0][rcA + ((ILO) + ii) * 1024 + colk0]; \
    Af[ii][1] = *(const bf16x8*)&lds[BUF][0][rcA + ((ILO) + ii) * 1024 + colk1]; } }
#define RDB(BUF, JLO) {                                                    \
  _Pragma("unroll") for (int jj = 0; jj < 2; ++jj) {                       \
    Bf[(JLO) + jj][0] = *(const bf16x8*)&lds[BUF][1][rcB + ((JLO) + jj) * 1024 + colk0]; \
    Bf[(JLO) + jj][1] = *(const bf16x8*)&lds[BUF][1][rcB + ((JLO) + jj) * 1024 + colk1]; } }
#define MM(ILO, JLO) {                                                     \
  _Pragma("unroll") for (int ii = 0; ii < 4; ++ii)                         \
  _Pragma("unroll") for (int jj = 0; jj < 2; ++jj) {                       \
    acc[(ILO)+ii][(JLO)+jj] = __builtin_amdgcn_mfma_f32_16x16x32_bf16(Af[ii][0], Bf[(JLO)+jj][0], acc[(ILO)+ii][(JLO)+jj], 0, 0, 0); \
    acc[(ILO)+ii][(JLO)+jj] = __builtin_amdgcn_mfma_f32_16x16x32_bf16(Af[ii][1], Bf[(JLO)+jj][1], acc[(ILO)+ii][(JLO)+jj], 0, 0, 0); } }
#define BAR() __builtin_amdgcn_s_barrier()
#define PRIO(x) __builtin_amdgcn_s_setprio(x)

  // prologue: T0 all 4 halves + T1's B halves; vmcnt(4) -> T0 landed
  STG(0, 0, 0, lda, gAs); STG(0, 0, 1, lda, gAs);
  STG(0, 1, 0, ldb, gBs); STG(0, 1, 1, ldb, gBs);
  STG(1, 1, 0, ldb, gBs); STG(1, 1, 1, ldb, gBs);
  asm volatile("s_waitcnt vmcnt(4)" ::: "memory");
  SB0(); BAR();

  for (int it = 0; it < NIT; ++it) {
    const int T0 = it << 1, T1 = T0 + 1;
    // ---- P1: Q0 of T0 ----
    RDB(0, 0); RDA(0, 0); STG(T1, 0, 0, lda, gAs);
    BAR();
    PRIO(1); MM(0, 0); PRIO(0); BAR();
    // ---- P2: Q1 of T0 ----
    RDB(0, 2); STG(T1, 0, 1, lda, gAs);
    BAR();
    PRIO(1); MM(0, 2); PRIO(0); BAR();
    // ---- P3: Q2 of T0 ----
    RDA(0, 4); STG(T0 + 2, 1, 0, ldb, gBs);
    BAR();
    PRIO(1); MM(4, 0); PRIO(0); BAR();
    // ---- P4: Q3 of T0 + counted vmcnt ----
    STG(T0 + 2, 1, 1, ldb, gBs);
    BAR();
    PRIO(1); MM(4, 2); PRIO(0);
    if (T0 + 2 < KT) { asm volatile("s_waitcnt vmcnt(4)" ::: "memory"); }
    else             { asm volatile("s_waitcnt vmcnt(0)" ::: "memory"); }
    SB0(); BAR();
    // ---- P5: Q0 of T1 ----
    RDB(1, 0); RDA(1, 0); STG(T0 + 2, 0, 0, lda, gAs);
    BAR();
    PRIO(1); MM(0, 0); PRIO(0); BAR();
    // ---- P6: Q1 of T1 ----
    RDB(1, 2); STG(T0 + 2, 0, 1, lda, gAs);
    BAR();
    PRIO(1); MM(0, 2); PRIO(0); BAR();
    // ---- P7: Q2 of T1 ----
    RDA(1, 4); STG(T0 + 3, 1, 0, ldb, gBs);
    BAR();
    PRIO(1); MM(4, 0); PRIO(0); BAR();
    // ---- P8: Q3 of T1 + counted vmcnt ----
    STG(T0 + 3, 1, 1, ldb, gBs);
    BAR();
    PRIO(1); MM(4, 2); PRIO(0);
    if (T0 + 3 < KT) { asm volatile("s_waitcnt vmcnt(4)" ::: "memory"); }
    SB0(); BAR();
  }
#undef STG
#undef RDA
#undef RDB
#undef MM
#undef BAR
#undef PRIO

  // ---------------- epilogue (frag D row=(lhi*4+r), col=l15; m89-verified) ----------------
  const size_t cb = (size_t)bz * (size_t)sC;

  if (MODE == 5) {
    // MLP2: bias+relu then dot with W3 -> atomic logits; no C write.
    float w3v[4];
#pragma unroll
    for (int j = 0; j < 4; ++j) w3v[j] = w3[n0 + wn + j * 16 + l15];
#pragma unroll
    for (int i = 0; i < 8; ++i) {
      const int rg = m0 + wm + i * 16 + lhi * 4;
#pragma unroll
      for (int r = 0; r < 4; ++r) {
        float s = 0.f;
#pragma unroll
        for (int j = 0; j < 4; ++j) {
          float v = acc[i][j][r] + bias[n0 + wn + j * 16 + l15];
          v = fmaxf(v, 0.f);
          s += v * w3v[j];
        }
        s += __shfl_xor(s, 1, 64); s += __shfl_xor(s, 2, 64);
        s += __shfl_xor(s, 4, 64); s += __shfl_xor(s, 8, 64);
        if (l15 == 0) atomicAdd(&lg[rg + r], s);
      }
    }
    return;
  }

  u16* ep = ((u16*)lds) + wv * 8192;  // [128 rows][64 cols] wave-private bounce

  if (MODE == 3) {
    // scores: E = exp(scale*acc) masked, bf16 out + rowsum of quantized E.
#pragma unroll
    for (int i = 0; i < 8; ++i) {
#pragma unroll
      for (int r = 0; r < 4; ++r) {
        const int rr = m0 + wm + i * 16 + lhi * 4 + r;      // row in [0,1024)
        const int mk = (rr < 512) ? mk1[bz * 512 + rr] : mk2[bz * 512 + rr - 512];
        const int lrow = i * 16 + lhi * 4 + r;
        float s = 0.f;
#pragma unroll
        for (int j = 0; j < 4; ++j) {
          float e = (mk != 0) ? __expf(acc[i][j][r] * scale) : 0.f;
          const u16 eb = f2b(e);
          s += b2f(eb);
          const int lcol = (j * 16 + l15) ^ (((lrow >> 2) & 7) << 3);
          ep[lrow * 64 + lcol] = eb;
        }
        s += __shfl_xor(s, 1, 64); s += __shfl_xor(s, 2, 64);
        s += __shfl_xor(s, 4, 64); s += __shfl_xor(s, 8, 64);
        if (l15 == 0) atomicAdd(&rsw[(size_t)bz * 1024 + rr], s);
      }
    }
  } else {
    // MODE 0/1/2/4: standard fused epilogue into bounce
#pragma unroll
    for (int i = 0; i < 8; ++i) {
      const int rl = wm + i * 16 + lhi * 4;
      float rv[4];
#pragma unroll
      for (int r = 0; r < 4; ++r) {
        if (MODE == 2)      rv[r] = bias[m0 + rl + r];
        else if (MODE == 4) rv[r] = 1.f / rsw[(size_t)bz * 1024 + m0 + rl + r];
        else                rv[r] = 0.f;
      }
#pragma unroll
      for (int j = 0; j < 4; ++j) {
        const float cbv = (MODE == 0 || MODE == 1) ? bias[n0 + wn + j * 16 + l15] : 0.f;
#pragma unroll
        for (int r = 0; r < 4; ++r) {
          float v;
          if (MODE == 4)      v = acc[i][j][r] * rv[r];
          else if (MODE == 2) v = acc[i][j][r] + rv[r];
          else                v = acc[i][j][r] + cbv;
          if (MODE == 1) v = fmaxf(v, 0.f);
          const int lrow = i * 16 + lhi * 4 + r;
          const int lcol = (j * 16 + l15) ^ (((lrow >> 2) & 7) << 3);
          ep[lrow * 64 + lcol] = f2b(v);
        }
      }
    }
  }
  asm volatile("s_waitcnt lgkmcnt(0)" ::: "memory");  // own bounce writes landed
  SB0();
  const int l3 = ln >> 3, c0 = (ln & 7) * 8;
#pragma unroll
  for (int rep = 0; rep < 16; ++rep) {
    const int lr = rep * 8 + l3;
    const int cs = c0 ^ (((lr >> 2) & 7) << 3);
    u16x8 v = *(const u16x8*)&ep[lr * 64 + cs];
    *(u16x8*)((u16*)C + cb + (size_t)(m0 + wm + lr) * ldc + n0 + wn + c0) = v;
  }
}

// ---------- final: out = sigmoid(logits + b3) ----------
__global__ __launch_bounds__(256) void sigmoid_k(
    const float* __restrict__ lg, const float* __restrict__ b3, float* __restrict__ out) {
  const int i = blockIdx.x * 256 + threadIdx.x;
  out[i] = 1.f / (1.f + __expf(-(lg[i] + b3[0])));
}

// ---------- launcher ----------
extern "C" void kernel_launch(void* const* d_in, const int* in_sizes, int n_in,
                              void* d_out, int out_size, void* d_ws, size_t ws_size,
                              hipStream_t stream) {
  (void)in_sizes; (void)n_in; (void)out_size; (void)ws_size;
  const float* emb1 = (const float*)d_in[0];
  const float* emb2 = (const float*)d_in[1];
  const int*   mask1 = (const int*)d_in[2];
  const int*   mask2 = (const int*)d_in[3];
  const float* Wq = (const float*)d_in[4];  const float* bq = (const float*)d_in[5];
  const float* Wk = (const float*)d_in[6];  const float* bk = (const float*)d_in[7];
  const float* Wv = (const float*)d_in[8];  const float* bv = (const float*)d_in[9];
  const float* W1 = (const float*)d_in[10]; const float* b1 = (const float*)d_in[11];
  const float* W2 = (const float*)d_in[12]; const float* b2 = (const float*)d_in[13];
  const float* W3 = (const float*)d_in[14]; const float* b3 = (const float*)d_in[15];

  // ws layout (bytes), hand-aliased; peak ~183 MiB
  char* ws = (char*)d_ws;
  u16*  XB    = (u16*)(ws + 0);            // [16384][1024] bf16; later E (scores exp)
  u16*  QK    = (u16*)(ws + 33554432);     // [16384][2048] bf16 (Q|K); later H1
  u16*  VT    = (u16*)(ws + 100663296);    // [1024][16384] bf16 (V^T)
  u16*  ATT   = (u16*)(ws + 134217728);    // [16384][1024] bf16 (attended)
  u16*  WTQKV = (u16*)(ws + 167772160);    // [3072][1024] bf16
  u16*  W1T   = (u16*)(ws + 174063616);    // [2048][1024] bf16
  u16*  W2T   = (u16*)(ws + 178257920);    // [1024][2048] bf16
  float* BF_  = (float*)(ws + 182452224);  // [2048] f32 (bq|bk)
  float* RS   = (float*)(ws + 182460416);  // [16][1024] f32 rowsums (zeroed per call)
  float* LG   = (float*)(ws + 182525952);  // [16384] f32 logits (zeroed per call)
  u16*  E     = XB;                        // XB dead after V-GEMM
  u16*  H1    = QK;                        // QK dead after scores GEMM
  float* out  = (float*)d_out;

  const float SCALE = 0.04419417382415922f;  // 1/sqrt(512)

  hipMemsetAsync(RS, 0, 131072, stream);   // RS (64KB) + LG (64KB), adjacent

  prep<<<9992, 256, 0, stream>>>(emb1, emb2, XB, Wq, Wk, Wv, W1, W2,
                                 WTQKV, W1T, W2T, bq, bk, BF_);

  // Q|K: [16384,1024] x [1024,2048]^T-layout -> bf16 [16384,2048]
  gemm256<0><<<dim3(8, 64, 1), 512, 0, stream>>>(
      XB, 1024, 0, WTQKV, 1024, 0, QK, 2048, 0, BF_, 1.f, 1024,
      nullptr, nullptr, nullptr, nullptr, nullptr);
  // V^T: VT[d, b*S+s] = sum_k WvT[d,k]*XB[b*S+s,k] + bv[d] (row bias)
  gemm256<2><<<dim3(64, 4, 1), 512, 0, stream>>>(
      WTQKV + 2048 * 1024, 1024, 0, XB, 1024, 0, VT, 16384, 0, bv, 1.f, 1024,
      nullptr, nullptr, nullptr, nullptr, nullptr);
  // E = exp(scale * Q K^T) masked, + rowsums (softmax fused; no max pass)
  gemm256<3><<<dim3(4, 4, 16), 512, 0, stream>>>(
      QK, 2048, 2097152LL, QK + 1024, 2048, 2097152LL,
      E, 1024, 1048576LL, nullptr, SCALE, 1024,
      mask1, mask2, RS, nullptr, nullptr);
  // attended = (E @ V) / rowsum
  gemm256<4><<<dim3(4, 4, 16), 512, 0, stream>>>(
      E, 1024, 1048576LL, VT, 16384, 1024LL,
      ATT, 1024, 1048576LL, nullptr, 1.f, 1024,
      nullptr, nullptr, RS, nullptr, nullptr);
  // MLP1: relu(ATT x W1 + b1) -> H1
  gemm256<1><<<dim3(8, 64, 1), 512, 0, stream>>>(
      ATT, 1024, 0, W1T, 1024, 0, H1, 2048, 0, b1, 1.f, 1024,
      nullptr, nullptr, nullptr, nullptr, nullptr);
  // MLP2 fused with logits dot: relu(H1 x W2 + b2) . W3 -> LG (no H2 write)
  gemm256<5><<<dim3(4, 64, 1), 512, 0, stream>>>(
      H1, 2048, 0, W2T, 2048, 0, nullptr, 1024, 0, b2, 1.f, 2048,
      nullptr, nullptr, nullptr, W3, LG);
  sigmoid_k<<<64, 256, 0, stream>>>(LG, b3, out);
}